// Round 8
// baseline (4370.848 us; speedup 1.0000x reference)
//
#include <hip/hip_runtime.h>
#include <stdint.h>

// NpiLstm: T=512, B=128, H=1024, IN=64 (63 x-features + 1 feedback)
// Feedback folded into recurrent weights: W_hh' = W_hh + w_fb (x) W_lin.
// R8: 512 persistent blocks (2/CU); 8 groups x 64 blocks; group g = batch
// rows [16g,16g+16); block mb owns h-cols [16mb,16mb+16) => 64 gate-cols
// => weights = 147KB/block = 144 regs/lane -> UNDER the 256-reg ceiling, so
// the def-by-asm pin actually yields register residency (R5-R7: 294KB/block
// = 288 regs could never fit; compiler spilled/streamed every step ~1us).
// Exchange protocol unchanged (sc0 sc1 coherence point, proven R2/R5).

typedef short short8 __attribute__((ext_vector_type(8)));
typedef float float4v __attribute__((ext_vector_type(4)));
typedef int int4v __attribute__((ext_vector_type(4)));
typedef int int2v __attribute__((ext_vector_type(2)));

#define KP 1152      // padded K: 63 x | 1 zero | 1024 h | 64 zero-pad

__device__ __forceinline__ unsigned short f2bf(float f) {
  unsigned int u = __float_as_uint(f);
  u += 0x7fffu + ((u >> 16) & 1u);   // RNE
  return (unsigned short)(u >> 16);
}
__device__ __forceinline__ float sigm(float x) { return 1.0f / (1.0f + __expf(-x)); }
__device__ __forceinline__ float tanh_f(float x) {
  float ax = fabsf(x);
  float e = __expf(-2.0f * ax);
  float r = (1.0f - e) / (1.0f + e);
  return x < 0.0f ? -r : r;
}

// ---- build W_cat [4096][1152] bf16 and biases b1/b2 [4096] f32 ----
__global__ void prep_w(const float* __restrict__ W_ih, const float* __restrict__ W_hh,
                       const float* __restrict__ W_lin, const float* __restrict__ b_ih,
                       const float* __restrict__ b_hh, const float* __restrict__ b_lin,
                       unsigned short* __restrict__ Wcat, float* __restrict__ b1,
                       float* __restrict__ b2) {
  int idx = blockIdx.x * 256 + threadIdx.x;
  if (idx < 4096 * KP) {
    int j = idx / KP;
    int k = idx - j * KP;
    float v = 0.0f;
    if (k < 63) v = W_ih[j * 64 + k];
    else if (k >= 64 && k < 1088) {
      int kk = k - 64;
      v = W_hh[j * 1024 + kk] + W_ih[j * 64 + 63] * W_lin[kk];
    }
    Wcat[idx] = f2bf(v);
  }
  if (idx < 4096) {
    float wfb = W_ih[idx * 64 + 63];
    float base = b_ih[idx] + b_hh[idx];
    b1[idx] = base + 1e-9f * wfb;      // step 1: feedback value is INIT_OUT
    b2[idx] = base + b_lin[0] * wfb;   // steps >=2: folded b_lin feedback
  }
}

// ---- x -> bf16, padded to 64 channels ----
__global__ void prep_x(const float* __restrict__ x, unsigned short* __restrict__ xbf) {
  int idx = blockIdx.x * 256 + threadIdx.x;   // < 512*128*64 exactly
  int c = idx & 63;
  int bi = idx >> 6;
  unsigned short v = 0;
  if (c < 63) v = f2bf(x[bi * 63 + c]);
  xbf[idx] = v;
}

// ---- zero h0 buffers + flags ----
__global__ void initk(unsigned int* __restrict__ Hz, int* __restrict__ flags) {
  int idx = blockIdx.x * 256 + threadIdx.x;   // 0..65535
  Hz[idx] = 0u;
  Hz[idx + 65536] = 0u;
  if (idx < 2048) flags[idx] = 0;
}

// ---- persistent recurrent kernel: 512 blocks (2/CU), 256 threads ----
// wave wv handles K-tiles kt in [9wv, 9wv+9): kt 0,1 = x; kt 2..33 = h-chunk
// (kt-2) (32 cols, produced by blocks 2(kt-2), 2(kt-2)+1); kt 34,35 = pad.
__global__ __launch_bounds__(256, 2) void lstm_rec(
    const unsigned short* __restrict__ Wcat, const unsigned short* __restrict__ xbf,
    const float* __restrict__ b1, const float* __restrict__ b2,
    const float* __restrict__ Wlin, unsigned short* __restrict__ Hbuf,
    float* __restrict__ outp, int* __restrict__ flags) {
  const int tid = threadIdx.x;
  const int bid = blockIdx.x;
  const int g = bid & 7;
  const int mb = bid >> 3;            // [0,64)
  const int wv = tid >> 6;
  const int ln = tid & 63;
  const int lr = ln & 15;             // MFMA fragment row/col within 16
  const int lq = ln >> 4;             // k-quarter
  const int prow = tid >> 4;          // pointwise row 0..15
  const int pcol = tid & 15;          // pointwise col 0..15

  __shared__ __align__(16) float pbuf[2][4][4][16][20];  // dbuf [wave][gate][col][row+pad]

  // ---- load B fragments (folded weights): 4 gates x 9 K-tiles = 144 regs; PIN ----
  short8 bf[4][9];
#pragma unroll
  for (int n = 0; n < 4; ++n) {
    const unsigned short* wrow = Wcat + (size_t)(n * 1024 + mb * 16 + lr) * KP;
#pragma unroll
    for (int j = 0; j < 9; ++j)
      bf[n][j] = *reinterpret_cast<const short8*>(wrow + (wv * 9 + j) * 32 + lq * 8);
  }
#pragma unroll
  for (int n = 0; n < 4; ++n)
#pragma unroll
    for (int j = 0; j < 9; ++j)
      asm volatile("" : "+v"(bf[n][j]));   // def-by-asm: no remat; fits -> resident

  // ---- K-tile geometry for this wave ----
  const int kb = wv * 9;
  const int jlo = (kb < 2) ? 2 : 0;          // first h-tile local index
  const int jhi = (kb + 9 > 34) ? 7 : 9;     // one past last h-tile local index
  const int cmin = (kb < 2) ? 0 : kb - 2;    // h-chunk (32-col) range
  const int cmax = (kb + 6 < 31) ? kb + 6 : 31;
  const int cnt = 8 * (cmax - cmin + 1);     // flags (4/block, 2 blocks/chunk) <= 72
  const int half = cnt >> 1;
  const int* fp = flags + g * 256 + 8 * cmin + 2 * ((ln < half) ? ln : half - 1);

  int hoff[9];   // per-tile byte offset into H slice (frag layout)
#pragma unroll
  for (int j = 0; j < 9; ++j)
    hoff[j] = ((g * 16 + lr) * 1024 + (kb + j - 2) * 32 + lq * 8) * 2;

  const int gcb = mb * 16 + pcol;   // this thread's gate/h column
  float bias2[4];
#pragma unroll
  for (int q = 0; q < 4; ++q) bias2[q] = b2[q * 1024 + gcb];
  const float wl = Wlin[gcb];
  float cs = 0.f;                   // cell state (1 per thread) in register

  for (int t = 1; t < 512; ++t) {
    const int tm1 = t - 1;
    // --- x prefetch (no dependency on flags; only wave 0 consumes) ---
    short8 xa0, xa1;
    if (kb == 0) {
      const unsigned short* xrow =
          xbf + (size_t)t * 8192 + (g * 16 + lr) * 64 + lq * 8;
      xa0 = *reinterpret_cast<const short8*>(xrow);
      xa1 = *reinterpret_cast<const short8*>(xrow + 32);
    }

    // --- partial wait: poll only THIS wave's producers ---
    if (t > 1) {
      int guard = 0;
      for (;;) {
        int2v ff;
        asm volatile("global_load_dwordx2 %0, %1, off sc0 sc1\n\ts_waitcnt vmcnt(0)"
                     : "=v"(ff) : "v"(fp) : "memory");
        if (__all((ff.x >= tm1) && (ff.y >= tm1))) break;
        if (++guard > (1 << 18)) break;   // hang-safety valve
      }
    }

    // --- A-fragments: direct global->register in MFMA layout ---
    const unsigned short* hb = Hbuf + ((t - 1) & 1) * 131072;
    short8 af[9];
    if (kb == 0) { af[0] = xa0; af[1] = xa1; }
    if (jhi == 7) {
      short8 z8 = {0, 0, 0, 0, 0, 0, 0, 0};
      af[7] = z8; af[8] = z8;
    }
#pragma unroll
    for (int j = 0; j < 9; ++j)
      if (j >= jlo && j < jhi)
        asm volatile("global_load_dwordx4 %0, %1, %2 sc0 sc1"
                     : "=v"(af[j]) : "v"(hoff[j]), "s"(hb));
    asm volatile("s_waitcnt vmcnt(0)" ::: "memory");
    __builtin_amdgcn_sched_barrier(0);

    // --- MFMA: 4 gate-tiles x 9 K-tiles (K-split across waves) ---
    float4v acc[4];
#pragma unroll
    for (int n = 0; n < 4; ++n) acc[n] = (float4v){0.f, 0.f, 0.f, 0.f};
#pragma unroll
    for (int j = 0; j < 9; ++j)
#pragma unroll
      for (int n = 0; n < 4; ++n)
        acc[n] = __builtin_amdgcn_mfma_f32_16x16x32_bf16(af[j], bf[n][j], acc[n], 0, 0, 0);

    // --- partials to LDS (dbuf) ---
#pragma unroll
    for (int n = 0; n < 4; ++n)
      *reinterpret_cast<float4v*>(&pbuf[t & 1][wv][n][lr][lq * 4]) = acc[n];
    __syncthreads();   // the ONLY barrier per step

    // --- pointwise: reduce 4 wave-partials, gates -> c,h (1 value/thread) ---
    float ga[4];
#pragma unroll
    for (int q = 0; q < 4; ++q) {
      const float* pp0 = &pbuf[t & 1][0][q][pcol][prow];
      ga[q] = pp0[0] + pp0[4 * 16 * 20] + pp0[2 * 4 * 16 * 20] + pp0[3 * 4 * 16 * 20];
    }
    float lb0 = bias2[0], lb1 = bias2[1], lb2 = bias2[2], lb3 = bias2[3];
    if (t == 1) {
      lb0 = b1[gcb];
      lb1 = b1[1024 + gcb];
      lb2 = b1[2048 + gcb];
      lb3 = b1[3072 + gcb];
    }
    float iv = sigm(ga[0] + lb0), fv = sigm(ga[1] + lb1);
    float Gv = tanh_f(ga[2] + lb2), ov = sigm(ga[3] + lb3);
    cs = fv * cs + iv * Gv;
    float hv = ov * tanh_f(cs);

    // --- publish h (coherence point), drain, per-wave flag ---
    unsigned short* Hd = Hbuf + (t & 1) * 131072;
    unsigned short* p0 = Hd + (size_t)(g * 16 + prow) * 1024 + gcb;
    int hb0 = (int)f2bf(hv);
    asm volatile("global_store_short %0, %1, off sc0 sc1" :: "v"(p0), "v"(hb0) : "memory");
    asm volatile("s_waitcnt vmcnt(0)" ::: "memory");
    if (ln == 0) {
      int* fp2 = flags + g * 256 + mb * 4 + wv;
      asm volatile("global_store_dword %0, %1, off sc0 sc1" :: "v"(fp2), "v"(t) : "memory");
    }

    // --- W_lin partial for this block's 16 cols (after flag; off-chain) ---
    float pa = hv * wl;
    pa += __shfl_xor(pa, 1);
    pa += __shfl_xor(pa, 2);
    pa += __shfl_xor(pa, 4);
    pa += __shfl_xor(pa, 8);
    if (pcol == 0)
      outp[(size_t)(t * 128 + g * 16 + prow) * 64 + mb] = pa;
  }
}

// ---- out[t][b] = b_lin + sum_mb outp[t][b][mb]; rows t=0 -> INIT_OUT ----
__global__ void finalize(const float* __restrict__ outp, const float* __restrict__ b_lin,
                         float* __restrict__ out) {
  int tid = threadIdx.x;
  int ln = tid & 63;
  int wv = tid >> 6;
  int row = blockIdx.x * 4 + wv;   // < 65536
  float v = outp[(size_t)row * 64 + ln];
  v += __shfl_xor(v, 1);
  v += __shfl_xor(v, 2);
  v += __shfl_xor(v, 4);
  v += __shfl_xor(v, 8);
  v += __shfl_xor(v, 16);
  v += __shfl_xor(v, 32);
  if (ln == 0) out[row] = (row < 128) ? 1e-9f : (v + b_lin[0]);
}

extern "C" void kernel_launch(void* const* d_in, const int* in_sizes, int n_in,
                              void* d_out, int out_size, void* d_ws, size_t ws_size,
                              hipStream_t stream) {
  const float* x = (const float*)d_in[0];
  const float* W_ih = (const float*)d_in[1];
  const float* W_hh = (const float*)d_in[2];
  const float* b_ih = (const float*)d_in[3];
  const float* b_hh = (const float*)d_in[4];
  const float* W_lin = (const float*)d_in[5];
  const float* b_lin = (const float*)d_in[6];
  float* out = (float*)d_out;

  char* ws = (char*)d_ws;
  const size_t WS_WCAT = 0;                  // 4096*1152*2   = 9437184
  const size_t WS_XBF  = 9437184;            // 512*128*64*2  = 8388608
  const size_t WS_B1   = 17825792;           // 16384
  const size_t WS_B2   = 17842176;           // 16384
  const size_t WS_H    = 17858560;           // 2*128*1024*2  = 524288
  const size_t WS_OUTP = 18382848;           // 512*128*64*4  = 16777216
  const size_t WS_END  = 35160064;
  if (ws_size < WS_END) return;              // insufficient scratch -> fail loudly

  unsigned short* Wcat = (unsigned short*)(ws + WS_WCAT);
  unsigned short* xbf = (unsigned short*)(ws + WS_XBF);
  float* b1 = (float*)(ws + WS_B1);
  float* b2 = (float*)(ws + WS_B2);
  unsigned short* Hbuf = (unsigned short*)(ws + WS_H);
  float* outp = (float*)(ws + WS_OUTP);
  int* flags = (int*)(ws + WS_OUTP);         // aliases outp floats 0..2047 (t=0 rows, unused)

  prep_w<<<18432, 256, 0, stream>>>(W_ih, W_hh, W_lin, b_ih, b_hh, b_lin, Wcat, b1, b2);
  prep_x<<<16384, 256, 0, stream>>>(x, xbf);
  initk<<<256, 256, 0, stream>>>((unsigned int*)Hbuf, flags);
  lstm_rec<<<512, 256, 0, stream>>>(Wcat, xbf, b1, b2, W_lin, Hbuf, outp, flags);
  finalize<<<16384, 256, 0, stream>>>(outp, b_lin, out);
}

// Round 9
// 3337.535 us; speedup vs baseline: 1.3096x; 1.3096x over previous
//
#include <hip/hip_runtime.h>
#include <stdint.h>

// NpiLstm: T=512, B=128, H=1024, IN=64 (63 x-features + 1 feedback)
// Feedback folded into recurrent weights: W_hh' = W_hh + w_fb (x) W_lin.
// R9: weights LDS-RESIDENT (loaded once; LDS can't be spilled/remat'd by
// the compiler — R5-R8 proved register residency is unattainable at any
// geometry: the allocator streams/spills ~294KB/block/step from IC, the
// dominant serial cost). 256 blocks (1/CU); 4 groups x 64 blocks; group g
// = batch rows [32g,32g+32); block mb owns h-cols [16mb,16mb+16).
// Wave wv = K-tiles [8wv..8wv+8) of h (+ x-tile wv for waves 0,1);
// 30 h-tiles of W in LDS (120KB), x-tiles + h-tiles 30,31 in registers.
// Per-wave flag poll: exactly 16 producer blocks x 4 waves = 64 flags.
// Exchange at coherence point (sc0 sc1) — proven R2/R5.

typedef short short8 __attribute__((ext_vector_type(8)));
typedef float float4v __attribute__((ext_vector_type(4)));
typedef int int4v __attribute__((ext_vector_type(4)));

#define KP 1152      // Wcat padded K: 63 x | 1 zero | 1024 h | 64 zero-pad

__device__ __forceinline__ unsigned short f2bf(float f) {
  unsigned int u = __float_as_uint(f);
  u += 0x7fffu + ((u >> 16) & 1u);   // RNE
  return (unsigned short)(u >> 16);
}
__device__ __forceinline__ float sigm(float x) { return 1.0f / (1.0f + __expf(-x)); }
__device__ __forceinline__ float tanh_f(float x) {
  float ax = fabsf(x);
  float e = __expf(-2.0f * ax);
  float r = (1.0f - e) / (1.0f + e);
  return x < 0.0f ? -r : r;
}

// ---- build W_cat [4096][1152] bf16 and biases b1/b2 [4096] f32 ----
__global__ void prep_w(const float* __restrict__ W_ih, const float* __restrict__ W_hh,
                       const float* __restrict__ W_lin, const float* __restrict__ b_ih,
                       const float* __restrict__ b_hh, const float* __restrict__ b_lin,
                       unsigned short* __restrict__ Wcat, float* __restrict__ b1,
                       float* __restrict__ b2) {
  int idx = blockIdx.x * 256 + threadIdx.x;
  if (idx < 4096 * KP) {
    int j = idx / KP;
    int k = idx - j * KP;
    float v = 0.0f;
    if (k < 63) v = W_ih[j * 64 + k];
    else if (k >= 64 && k < 1088) {
      int kk = k - 64;
      v = W_hh[j * 1024 + kk] + W_ih[j * 64 + 63] * W_lin[kk];
    }
    Wcat[idx] = f2bf(v);
  }
  if (idx < 4096) {
    float wfb = W_ih[idx * 64 + 63];
    float base = b_ih[idx] + b_hh[idx];
    b1[idx] = base + 1e-9f * wfb;      // step 1: feedback value is INIT_OUT
    b2[idx] = base + b_lin[0] * wfb;   // steps >=2: folded b_lin feedback
  }
}

// ---- x -> bf16, padded to 64 channels ----
__global__ void prep_x(const float* __restrict__ x, unsigned short* __restrict__ xbf) {
  int idx = blockIdx.x * 256 + threadIdx.x;   // < 512*128*64 exactly
  int c = idx & 63;
  int bi = idx >> 6;
  unsigned short v = 0;
  if (c < 63) v = f2bf(x[bi * 63 + c]);
  xbf[idx] = v;
}

// ---- zero h0 buffers + flags ----
__global__ void initk(unsigned int* __restrict__ Hz, int* __restrict__ flags) {
  int idx = blockIdx.x * 256 + threadIdx.x;   // 0..65535
  Hz[idx] = 0u;
  Hz[idx + 65536] = 0u;
  if (idx < 1024) flags[idx] = 0;
}

// ---- persistent recurrent kernel: 256 blocks (1/CU), 256 threads ----
__global__ __launch_bounds__(256, 1) void lstm_rec(
    const unsigned short* __restrict__ Wcat, const unsigned short* __restrict__ xbf,
    const float* __restrict__ b1, const float* __restrict__ b2,
    const float* __restrict__ Wlin, unsigned short* __restrict__ Hbuf,
    float* __restrict__ outp, int* __restrict__ flags) {
  const int tid = threadIdx.x;
  const int bid = blockIdx.x;
  const int g = bid & 3;          // group: batch rows [32g, 32g+32)
  const int mb = bid >> 2;        // [0,64): h-cols [16mb, 16mb+16)
  const int wv = tid >> 6;
  const int ln = tid & 63;
  const int lr = ln & 15;         // MFMA fragment row/col within 16
  const int lq = ln >> 4;         // k-quarter
  const int rp = tid >> 4;        // pointwise: rows 2rp, 2rp+1 (rp 0..15)
  const int pcol = tid & 15;      // pointwise col 0..15

  __shared__ __align__(16) char wlds[122880];            // h-tiles 0..29 x 4 gates x 1024B
  __shared__ __align__(16) float pbuf[4][4][2][16][18];  // [wave][gate][m][col][row+pad]

  const int hb = wv * 8;          // this wave's first h-tile

  // ---- stage folded weights once: LDS tiles 0..29; regs: x (w0,w1), h30/31 (w3) ----
  short8 xw[4];      // wave 0: x-tile 0; wave 1: x-tile 1
  short8 rw[2][4];   // wave 3: h-tiles 30, 31
  {
    const unsigned short* wbase = Wcat + (size_t)(mb * 16 + lr) * KP;
#pragma unroll
    for (int jj = 0; jj < 8; ++jj) {
      int ht = hb + jj;
      if (ht < 30) {
#pragma unroll
        for (int n = 0; n < 4; ++n) {
          short8 v = *reinterpret_cast<const short8*>(
              wbase + (size_t)n * 1024 * KP + 64 + ht * 32 + lq * 8);
          *reinterpret_cast<short8*>(wlds + ((ht * 4 + n) << 10) + ln * 16) = v;
        }
      }
    }
    if (wv < 2) {
#pragma unroll
      for (int n = 0; n < 4; ++n) {
        xw[n] = *reinterpret_cast<const short8*>(
            wbase + (size_t)n * 1024 * KP + wv * 32 + lq * 8);
        asm volatile("" : "+v"(xw[n]));
      }
    }
    if (wv == 3) {
#pragma unroll
      for (int k = 0; k < 2; ++k)
#pragma unroll
        for (int n = 0; n < 4; ++n) {
          rw[k][n] = *reinterpret_cast<const short8*>(
              wbase + (size_t)n * 1024 * KP + 64 + (30 + k) * 32 + lq * 8);
          asm volatile("" : "+v"(rw[k][n]));
        }
    }
  }
  __syncthreads();

  // poll set: this wave's 16 producer blocks x 4 wave-flags = 64 flags (1/lane)
  const int* fp = flags + g * 256 + wv * 64 + ln;

  int hoff[8][2];   // A-frag byte offsets into H parity slice
#pragma unroll
  for (int j = 0; j < 8; ++j)
#pragma unroll
    for (int m = 0; m < 2; ++m)
      hoff[j][m] = ((g * 32 + m * 16 + lr) * 1024 + (hb + j) * 32 + lq * 8) * 2;

  const int gcb = mb * 16 + pcol;   // this thread's gate/h column
  float bias2[4];
#pragma unroll
  for (int q = 0; q < 4; ++q) bias2[q] = b2[q * 1024 + gcb];
  const float wl = Wlin[gcb];
  const int m_pw = rp >> 3;          // pointwise M-tile
  const int r16 = (rp & 7) * 2;      // row pair base within tile
  float cs0 = 0.f, cs1 = 0.f;        // cell state (rows 2rp, 2rp+1)

  for (int t = 1; t < 512; ++t) {
    const int tm1 = t - 1;
    // --- x A-frag prefetch (constant input, cached; waves 0,1 only) ---
    short8 ax0, ax1;
    if (wv < 2) {
      const unsigned short* xr =
          xbf + (size_t)t * 8192 + (g * 32 + lr) * 64 + wv * 32 + lq * 8;
      ax0 = *reinterpret_cast<const short8*>(xr);
      ax1 = *reinterpret_cast<const short8*>(xr + 16 * 64);
    }

    // --- partial wait: poll this wave's 64 producer flags ---
    if (t > 1) {
      int guard = 0;
      for (;;) {
        int v;
        asm volatile("global_load_dword %0, %1, off sc0 sc1\n\ts_waitcnt vmcnt(0)"
                     : "=v"(v) : "v"(fp) : "memory");
        if (__all(v >= tm1)) break;
        if (++guard > (1 << 18)) break;   // hang-safety valve
      }
    }

    // --- A h-frags: direct global->register in MFMA layout (IC scope) ---
    const unsigned short* hbase = Hbuf + ((t - 1) & 1) * 131072;
    short8 af[8][2];
#pragma unroll
    for (int j = 0; j < 8; ++j)
#pragma unroll
      for (int m = 0; m < 2; ++m)
        asm volatile("global_load_dwordx4 %0, %1, %2 sc0 sc1"
                     : "=v"(af[j][m]) : "v"(hoff[j][m]), "s"(hbase));
    asm volatile("s_waitcnt vmcnt(0)" ::: "memory");
    __builtin_amdgcn_sched_barrier(0);

    // --- MFMA: 4 gates x 2 M x (8 or 9) K-tiles; B from LDS/regs ---
    float4v acc[4][2];
#pragma unroll
    for (int n = 0; n < 4; ++n) {
      acc[n][0] = (float4v){0.f, 0.f, 0.f, 0.f};
      acc[n][1] = (float4v){0.f, 0.f, 0.f, 0.f};
    }
    if (wv < 2) {
#pragma unroll
      for (int n = 0; n < 4; ++n) {
        acc[n][0] = __builtin_amdgcn_mfma_f32_16x16x32_bf16(ax0, xw[n], acc[n][0], 0, 0, 0);
        acc[n][1] = __builtin_amdgcn_mfma_f32_16x16x32_bf16(ax1, xw[n], acc[n][1], 0, 0, 0);
      }
    }
#pragma unroll
    for (int j = 0; j < 8; ++j) {
      short8 bf0, bf1, bf2, bf3;
      if (hb + j < 30) {
        const char* p = wlds + (((hb + j) * 4) << 10) + ln * 16;
        bf0 = *reinterpret_cast<const short8*>(p);
        bf1 = *reinterpret_cast<const short8*>(p + 1024);
        bf2 = *reinterpret_cast<const short8*>(p + 2048);
        bf3 = *reinterpret_cast<const short8*>(p + 3072);
      } else {
        bf0 = rw[hb + j - 30][0];
        bf1 = rw[hb + j - 30][1];
        bf2 = rw[hb + j - 30][2];
        bf3 = rw[hb + j - 30][3];
      }
      acc[0][0] = __builtin_amdgcn_mfma_f32_16x16x32_bf16(af[j][0], bf0, acc[0][0], 0, 0, 0);
      acc[0][1] = __builtin_amdgcn_mfma_f32_16x16x32_bf16(af[j][1], bf0, acc[0][1], 0, 0, 0);
      acc[1][0] = __builtin_amdgcn_mfma_f32_16x16x32_bf16(af[j][0], bf1, acc[1][0], 0, 0, 0);
      acc[1][1] = __builtin_amdgcn_mfma_f32_16x16x32_bf16(af[j][1], bf1, acc[1][1], 0, 0, 0);
      acc[2][0] = __builtin_amdgcn_mfma_f32_16x16x32_bf16(af[j][0], bf2, acc[2][0], 0, 0, 0);
      acc[2][1] = __builtin_amdgcn_mfma_f32_16x16x32_bf16(af[j][1], bf2, acc[2][1], 0, 0, 0);
      acc[3][0] = __builtin_amdgcn_mfma_f32_16x16x32_bf16(af[j][0], bf3, acc[3][0], 0, 0, 0);
      acc[3][1] = __builtin_amdgcn_mfma_f32_16x16x32_bf16(af[j][1], bf3, acc[3][1], 0, 0, 0);
    }

    // --- partials to LDS ---
#pragma unroll
    for (int n = 0; n < 4; ++n)
#pragma unroll
      for (int m = 0; m < 2; ++m)
        *reinterpret_cast<float4v*>(&pbuf[wv][n][m][lr][lq * 4]) = acc[n][m];
    __syncthreads();   // bar1: partials visible

    // --- pointwise: reduce 4 wave-partials (rows 2rp, 2rp+1, col pcol) ---
    float ga0[4], ga1[4];
#pragma unroll
    for (int q = 0; q < 4; ++q) {
      ga0[q] = pbuf[0][q][m_pw][pcol][r16] + pbuf[1][q][m_pw][pcol][r16] +
               pbuf[2][q][m_pw][pcol][r16] + pbuf[3][q][m_pw][pcol][r16];
      ga1[q] = pbuf[0][q][m_pw][pcol][r16 + 1] + pbuf[1][q][m_pw][pcol][r16 + 1] +
               pbuf[2][q][m_pw][pcol][r16 + 1] + pbuf[3][q][m_pw][pcol][r16 + 1];
    }
    __syncthreads();   // bar2: pbuf reads done before next step's writes

    float lb0 = bias2[0], lb1 = bias2[1], lb2 = bias2[2], lb3 = bias2[3];
    if (t == 1) {
      lb0 = b1[gcb];
      lb1 = b1[1024 + gcb];
      lb2 = b1[2048 + gcb];
      lb3 = b1[3072 + gcb];
    }
    float i0 = sigm(ga0[0] + lb0), f0 = sigm(ga0[1] + lb1);
    float G0 = tanh_f(ga0[2] + lb2), o0 = sigm(ga0[3] + lb3);
    float i1 = sigm(ga1[0] + lb0), f1 = sigm(ga1[1] + lb1);
    float G1 = tanh_f(ga1[2] + lb2), o1 = sigm(ga1[3] + lb3);
    cs0 = f0 * cs0 + i0 * G0;
    cs1 = f1 * cs1 + i1 * G1;
    float h0v = o0 * tanh_f(cs0);
    float h1v = o1 * tanh_f(cs1);

    // --- publish h (coherence point), drain, per-wave flag ---
    const int grow = g * 32 + 2 * rp;
    unsigned short* Hd = Hbuf + (t & 1) * 131072;
    unsigned short* p0 = Hd + (size_t)grow * 1024 + gcb;
    unsigned short* p1 = p0 + 1024;
    int hb0 = (int)f2bf(h0v), hb1 = (int)f2bf(h1v);
    asm volatile("global_store_short %0, %1, off sc0 sc1" :: "v"(p0), "v"(hb0) : "memory");
    asm volatile("global_store_short %0, %1, off sc0 sc1" :: "v"(p1), "v"(hb1) : "memory");
    asm volatile("s_waitcnt vmcnt(0)" ::: "memory");
    if (ln == 0) {
      int* fp2 = flags + g * 256 + mb * 4 + wv;
      asm volatile("global_store_dword %0, %1, off sc0 sc1" :: "v"(fp2), "v"(t) : "memory");
    }

    // --- W_lin partial for this block's 16 cols (after flag; off-chain) ---
    float pa = h0v * wl, pb = h1v * wl;
    pa += __shfl_xor(pa, 1); pb += __shfl_xor(pb, 1);
    pa += __shfl_xor(pa, 2); pb += __shfl_xor(pb, 2);
    pa += __shfl_xor(pa, 4); pb += __shfl_xor(pb, 4);
    pa += __shfl_xor(pa, 8); pb += __shfl_xor(pb, 8);
    if (pcol == 0) {
      outp[(size_t)(t * 128 + grow) * 64 + mb] = pa;
      outp[(size_t)(t * 128 + grow + 1) * 64 + mb] = pb;
    }
  }
}

// ---- out[t][b] = b_lin + sum_mb outp[t][b][mb]; rows t=0 -> INIT_OUT ----
__global__ void finalize(const float* __restrict__ outp, const float* __restrict__ b_lin,
                         float* __restrict__ out) {
  int tid = threadIdx.x;
  int ln = tid & 63;
  int wv = tid >> 6;
  int row = blockIdx.x * 4 + wv;   // < 65536
  float v = outp[(size_t)row * 64 + ln];
  v += __shfl_xor(v, 1);
  v += __shfl_xor(v, 2);
  v += __shfl_xor(v, 4);
  v += __shfl_xor(v, 8);
  v += __shfl_xor(v, 16);
  v += __shfl_xor(v, 32);
  if (ln == 0) out[row] = (row < 128) ? 1e-9f : (v + b_lin[0]);
}

extern "C" void kernel_launch(void* const* d_in, const int* in_sizes, int n_in,
                              void* d_out, int out_size, void* d_ws, size_t ws_size,
                              hipStream_t stream) {
  const float* x = (const float*)d_in[0];
  const float* W_ih = (const float*)d_in[1];
  const float* W_hh = (const float*)d_in[2];
  const float* b_ih = (const float*)d_in[3];
  const float* b_hh = (const float*)d_in[4];
  const float* W_lin = (const float*)d_in[5];
  const float* b_lin = (const float*)d_in[6];
  float* out = (float*)d_out;

  char* ws = (char*)d_ws;
  const size_t WS_WCAT = 0;                  // 4096*1152*2   = 9437184
  const size_t WS_XBF  = 9437184;            // 512*128*64*2  = 8388608
  const size_t WS_B1   = 17825792;           // 16384
  const size_t WS_B2   = 17842176;           // 16384
  const size_t WS_H    = 17858560;           // 2*128*1024*2  = 524288
  const size_t WS_OUTP = 18382848;           // 512*128*64*4  = 16777216
  const size_t WS_END  = 35160064;
  if (ws_size < WS_END) return;              // insufficient scratch -> fail loudly

  unsigned short* Wcat = (unsigned short*)(ws + WS_WCAT);
  unsigned short* xbf = (unsigned short*)(ws + WS_XBF);
  float* b1 = (float*)(ws + WS_B1);
  float* b2 = (float*)(ws + WS_B2);
  unsigned short* Hbuf = (unsigned short*)(ws + WS_H);
  float* outp = (float*)(ws + WS_OUTP);
  int* flags = (int*)(ws + WS_OUTP);         // aliases outp t=0 rows (never read/written by lstm_rec)

  prep_w<<<18432, 256, 0, stream>>>(W_ih, W_hh, W_lin, b_ih, b_hh, b_lin, Wcat, b1, b2);
  prep_x<<<16384, 256, 0, stream>>>(x, xbf);
  initk<<<256, 256, 0, stream>>>((unsigned int*)Hbuf, flags);
  lstm_rec<<<256, 256, 0, stream>>>(Wcat, xbf, b1, b2, W_lin, Hbuf, outp, flags);
  finalize<<<16384, 256, 0, stream>>>(outp, b_lin, out);
}